// Round 1
// baseline (318.990 us; speedup 1.0000x reference)
//
#include <hip/hip_runtime.h>
#include <hip/hip_bf16.h>

typedef __attribute__((ext_vector_type(8))) short bf16x8;
typedef __attribute__((ext_vector_type(4))) float f32x4;

#define TOK  4096
#define OUTF 4096
#define INF  4096
#define KE   4128   // 4096 + 32 (16 lora cols + 16 zero pad)
#define RANKD 16

static __device__ __forceinline__ unsigned short f2b(float f) {
  __hip_bfloat16 b = __float2bfloat16(f);
  return __builtin_bit_cast(unsigned short, b);
}

static __device__ __forceinline__ void gload_lds16(const void* g, void* l) {
  __builtin_amdgcn_global_load_lds(
      (const __attribute__((address_space(1))) void*)g,
      (__attribute__((address_space(3))) void*)l, 16, 0, 0);
}

// ---------------- kernel 1: xA = x @ A (f32), [TOK][16] ----------------
__global__ __launch_bounds__(256) void k_xa(const float* __restrict__ x,
                                            const float* __restrict__ A,
                                            float* __restrict__ xA) {
  const int lane = threadIdx.x & 63;
  const int wave = threadIdx.x >> 6;
  const int m0 = blockIdx.x * 16 + wave * 4;   // 4 rows per wave
  float p[4][16];
#pragma unroll
  for (int a = 0; a < 4; ++a)
#pragma unroll
    for (int r = 0; r < 16; ++r) p[a][r] = 0.f;

  for (int k = lane; k < INF; k += 64) {
    const float4* a4 = (const float4*)&A[(size_t)k * RANKD];
    float av[16];
    *(float4*)&av[0]  = a4[0];
    *(float4*)&av[4]  = a4[1];
    *(float4*)&av[8]  = a4[2];
    *(float4*)&av[12] = a4[3];
#pragma unroll
    for (int rr = 0; rr < 4; ++rr) {
      const float xv = x[(size_t)(m0 + rr) * INF + k];
#pragma unroll
      for (int r = 0; r < 16; ++r) p[rr][r] = fmaf(xv, av[r], p[rr][r]);
    }
  }
#pragma unroll
  for (int rr = 0; rr < 4; ++rr)
#pragma unroll
    for (int r = 0; r < 16; ++r) {
      float v = p[rr][r];
      v += __shfl_xor(v, 1);
      v += __shfl_xor(v, 2);
      v += __shfl_xor(v, 4);
      v += __shfl_xor(v, 8);
      v += __shfl_xor(v, 16);
      v += __shfl_xor(v, 32);
      p[rr][r] = v;
    }
  if (lane == 0) {
#pragma unroll
    for (int rr = 0; rr < 4; ++rr)
#pragma unroll
      for (int r = 0; r < 16; ++r)
        xA[(size_t)(m0 + rr) * RANKD + r] = p[rr][r];
  }
}

// ------ kernel 2: Xe[m][0:4096]=bf16(x), [4096:4112]=bf16(2*xA), rest 0 ------
__global__ __launch_bounds__(256) void k_fill_xe(const float* __restrict__ x,
                                                 const float* __restrict__ xA,
                                                 unsigned short* __restrict__ Xe) {
  const int total = TOK * (KE / 4);   // 4096 * 1032 groups of 4 elems
  for (int tid = blockIdx.x * 256 + threadIdx.x; tid < total;
       tid += 2048 * 256) {
    const int m = tid / 1032;
    const int g = tid - m * 1032;
    ushort4 w;
    if (g < 1024) {
      const float4 v = *(const float4*)&x[(size_t)m * INF + g * 4];
      w.x = f2b(v.x); w.y = f2b(v.y); w.z = f2b(v.z); w.w = f2b(v.w);
    } else {
      const int kk = (g - 1024) * 4;   // 0..28
      float v0 = (kk + 0 < RANKD) ? 2.f * xA[(size_t)m * RANKD + kk + 0] : 0.f;
      float v1 = (kk + 1 < RANKD) ? 2.f * xA[(size_t)m * RANKD + kk + 1] : 0.f;
      float v2 = (kk + 2 < RANKD) ? 2.f * xA[(size_t)m * RANKD + kk + 2] : 0.f;
      float v3 = (kk + 3 < RANKD) ? 2.f * xA[(size_t)m * RANKD + kk + 3] : 0.f;
      w.x = f2b(v0); w.y = f2b(v1); w.z = f2b(v2); w.w = f2b(v3);
    }
    *(ushort4*)&Xe[(size_t)m * KE + g * 4] = w;
  }
}

// ------ kernel 3: We[o][0:4096]=bf16(dequant W), [4096:4112]=bf16(B[r][o]) ------
__global__ __launch_bounds__(256) void k_fill_we(const int* __restrict__ q,
                                                 const float* __restrict__ absmax,
                                                 const float* __restrict__ cb,
                                                 const float* __restrict__ B,
                                                 unsigned short* __restrict__ We) {
  __shared__ float cbs[16];
  if (threadIdx.x < 16) cbs[threadIdx.x] = cb[threadIdx.x];
  __syncthreads();
  const int total = OUTF * (KE / 4);
  for (int tid = blockIdx.x * 256 + threadIdx.x; tid < total;
       tid += 2048 * 256) {
    const int o = tid / 1032;
    const int g = tid - o * 1032;
    ushort4 w;
    if (g < 1024) {
      const int4 qc = *(const int4*)&q[(size_t)o * INF + g * 4];
      const float am = absmax[(size_t)o * 64 + (g >> 4)];
      w.x = f2b(cbs[qc.x] * am);
      w.y = f2b(cbs[qc.y] * am);
      w.z = f2b(cbs[qc.z] * am);
      w.w = f2b(cbs[qc.w] * am);
    } else {
      const int kk = (g - 1024) * 4;
      float v0 = (kk + 0 < RANKD) ? B[(size_t)(kk + 0) * OUTF + o] : 0.f;
      float v1 = (kk + 1 < RANKD) ? B[(size_t)(kk + 1) * OUTF + o] : 0.f;
      float v2 = (kk + 2 < RANKD) ? B[(size_t)(kk + 2) * OUTF + o] : 0.f;
      float v3 = (kk + 3 < RANKD) ? B[(size_t)(kk + 3) * OUTF + o] : 0.f;
      w.x = f2b(v0); w.y = f2b(v1); w.z = f2b(v2); w.w = f2b(v3);
    }
    *(ushort4*)&We[(size_t)o * KE + g * 4] = w;
  }
}

// ---------------- kernel 4: out = Xe @ We^T + bias ----------------
// 128x128 tile, BK=32, 4 waves (2x2), 16x16x32 bf16 MFMA, global_load_lds staging.
__global__ __launch_bounds__(256) void k_gemm(const unsigned short* __restrict__ Xe,
                                              const unsigned short* __restrict__ We,
                                              const float* __restrict__ bias,
                                              float* __restrict__ out) {
  __shared__ unsigned short As[128 * 32];   // 8 KB
  __shared__ unsigned short Bs[128 * 32];   // 8 KB

  // XCD-aware swizzle: 1024 blocks, 8 XCDs, 128 contiguous per XCD (bijective)
  const int wg = blockIdx.x;
  const int swz = (wg & 7) * 128 + (wg >> 3);
  const int tileRow = swz >> 5;   // 0..31
  const int tileCol = swz & 31;   // 0..31

  const int tid = threadIdx.x;
  const int lane = tid & 63;
  const int wave = tid >> 6;        // 0..3
  const int waveM = wave >> 1;      // 0..1
  const int waveN = wave & 1;       // 0..1

  // staging geometry: tile is [128 rows][32 cols] bf16 = 8192 B, linear.
  // wave stages 2 KB: bytes [wave*2048, wave*2048+2048), 2 instrs of 1 KB.
  const int o0 = wave * 2048 + lane * 16;          // byte offset in tile
  const int r0 = o0 >> 6;                          // row (64 B/row)
  const int e0 = (o0 & 63) >> 1;                   // elem within row
  const int r1 = r0 + 16;                          // +1024 B = +16 rows

  const unsigned short* gA0 = Xe + (size_t)(tileRow * 128 + r0) * KE + e0;
  const unsigned short* gA1 = Xe + (size_t)(tileRow * 128 + r1) * KE + e0;
  const unsigned short* gB0 = We + (size_t)(tileCol * 128 + r0) * KE + e0;
  const unsigned short* gB1 = We + (size_t)(tileCol * 128 + r1) * KE + e0;

  unsigned short* lA0 = As + wave * 1024;          // wave-uniform LDS bases
  unsigned short* lA1 = As + wave * 1024 + 512;
  unsigned short* lB0 = Bs + wave * 1024;
  unsigned short* lB1 = Bs + wave * 1024 + 512;

  f32x4 acc[4][4];
#pragma unroll
  for (int i = 0; i < 4; ++i)
#pragma unroll
    for (int j = 0; j < 4; ++j) acc[i][j] = f32x4{0.f, 0.f, 0.f, 0.f};

  const int fr = lane & 15;          // fragment row (m for A, n for B)
  const int fk = (lane >> 4) * 8;    // fragment k offset

  for (int t = 0; t < KE / 32; ++t) {   // 129 iterations
    if (t) __syncthreads();             // previous compute done before overwrite
    const int k0 = t * 32;
    gload_lds16(gA0 + k0, lA0);
    gload_lds16(gA1 + k0, lA1);
    gload_lds16(gB0 + k0, lB0);
    gload_lds16(gB1 + k0, lB1);
    __syncthreads();                    // vmcnt drained before barrier

    bf16x8 a[4], b[4];
#pragma unroll
    for (int i = 0; i < 4; ++i)
      a[i] = *(const bf16x8*)&As[(waveM * 64 + i * 16 + fr) * 32 + fk];
#pragma unroll
    for (int i = 0; i < 4; ++i)
      b[i] = *(const bf16x8*)&Bs[(waveN * 64 + i * 16 + fr) * 32 + fk];
#pragma unroll
    for (int i = 0; i < 4; ++i)
#pragma unroll
      for (int j = 0; j < 4; ++j)
        acc[i][j] =
            __builtin_amdgcn_mfma_f32_16x16x32_bf16(a[i], b[j], acc[i][j], 0, 0, 0);
  }

  // epilogue: C/D layout col = lane&15, row = (lane>>4)*4 + reg
  const int rq = (lane >> 4) * 4;
  const int mBase = tileRow * 128 + waveM * 64;
  const int nBase = tileCol * 128 + waveN * 64;
#pragma unroll
  for (int j2 = 0; j2 < 4; ++j2) {
    const int n = nBase + j2 * 16 + fr;
    const float bsv = bias[n];
#pragma unroll
    for (int i2 = 0; i2 < 4; ++i2) {
      const int m = mBase + i2 * 16 + rq;
#pragma unroll
      for (int e = 0; e < 4; ++e)
        out[(size_t)(m + e) * OUTF + n] = acc[i2][j2][e] + bsv;
    }
  }
}

extern "C" void kernel_launch(void* const* d_in, const int* in_sizes, int n_in,
                              void* d_out, int out_size, void* d_ws, size_t ws_size,
                              hipStream_t stream) {
  const float* x      = (const float*)d_in[0];
  const int*   q      = (const int*)d_in[1];
  const float* absmax = (const float*)d_in[2];
  const float* cb     = (const float*)d_in[3];
  const float* bias   = (const float*)d_in[4];
  const float* A      = (const float*)d_in[5];
  const float* B      = (const float*)d_in[6];
  float* out = (float*)d_out;

  unsigned short* Xe = (unsigned short*)d_ws;              // 4096*4128*2 B
  unsigned short* We = Xe + (size_t)TOK * KE;              // 4096*4128*2 B
  float* xA = (float*)(We + (size_t)OUTF * KE);            // 4096*16*4 B

  k_xa<<<TOK / 16, 256, 0, stream>>>(x, A, xA);
  k_fill_xe<<<2048, 256, 0, stream>>>(x, xA, Xe);
  k_fill_we<<<2048, 256, 0, stream>>>(q, absmax, cb, B, We);
  k_gemm<<<1024, 256, 0, stream>>>(Xe, We, bias, out);
}

// Round 2
// 213.571 us; speedup vs baseline: 1.4936x; 1.4936x over previous
//
#include <hip/hip_runtime.h>
#include <hip/hip_bf16.h>

typedef __attribute__((ext_vector_type(8))) short bf16x8;
typedef __attribute__((ext_vector_type(4))) float f32x4;

#define TOK   4096
#define OUTF  4096
#define INF   4096
#define KE    4160   // 4096 + 32 (16 lora cols + 16 zero) + 32 zero pad -> 130 K-tiles of 32
#define NT    130    // KE / 32
#define RANKD 16

static __device__ __forceinline__ unsigned short f2b(float f) {
  __hip_bfloat16 b = __float2bfloat16(f);
  return __builtin_bit_cast(unsigned short, b);
}

static __device__ __forceinline__ void gload_lds16(const void* g, void* l) {
  __builtin_amdgcn_global_load_lds(
      (const __attribute__((address_space(1))) void*)g,
      (__attribute__((address_space(3))) void*)l, 16, 0, 0);
}

// ---------------- kernel 1: xA = x @ A (f32), [TOK][16] ----------------
__global__ __launch_bounds__(256) void k_xa(const float* __restrict__ x,
                                            const float* __restrict__ A,
                                            float* __restrict__ xA) {
  const int lane = threadIdx.x & 63;
  const int wave = threadIdx.x >> 6;
  const int m0 = blockIdx.x * 16 + wave * 4;
  float p[4][16];
#pragma unroll
  for (int a = 0; a < 4; ++a)
#pragma unroll
    for (int r = 0; r < 16; ++r) p[a][r] = 0.f;

  for (int k = lane; k < INF; k += 64) {
    const float4* a4 = (const float4*)&A[(size_t)k * RANKD];
    float av[16];
    *(float4*)&av[0]  = a4[0];
    *(float4*)&av[4]  = a4[1];
    *(float4*)&av[8]  = a4[2];
    *(float4*)&av[12] = a4[3];
#pragma unroll
    for (int rr = 0; rr < 4; ++rr) {
      const float xv = x[(size_t)(m0 + rr) * INF + k];
#pragma unroll
      for (int r = 0; r < 16; ++r) p[rr][r] = fmaf(xv, av[r], p[rr][r]);
    }
  }
#pragma unroll
  for (int rr = 0; rr < 4; ++rr)
#pragma unroll
    for (int r = 0; r < 16; ++r) {
      float v = p[rr][r];
      v += __shfl_xor(v, 1);
      v += __shfl_xor(v, 2);
      v += __shfl_xor(v, 4);
      v += __shfl_xor(v, 8);
      v += __shfl_xor(v, 16);
      v += __shfl_xor(v, 32);
      p[rr][r] = v;
    }
  if (lane == 0) {
#pragma unroll
    for (int rr = 0; rr < 4; ++rr)
#pragma unroll
      for (int r = 0; r < 16; ++r)
        xA[(size_t)(m0 + rr) * RANKD + r] = p[rr][r];
  }
}

// ------ kernel 2: Xe[m][0:4096]=bf16(x), [4096:4112]=bf16(2*xA), rest 0 ------
__global__ __launch_bounds__(256) void k_fill_xe(const float* __restrict__ x,
                                                 const float* __restrict__ xA,
                                                 unsigned short* __restrict__ Xe) {
  const int total = TOK * (KE / 4);   // 4096 * 1040
  for (int tid = blockIdx.x * 256 + threadIdx.x; tid < total;
       tid += 2048 * 256) {
    const int m = tid / 1040;
    const int g = tid - m * 1040;
    ushort4 w;
    if (g < 1024) {
      const float4 v = *(const float4*)&x[(size_t)m * INF + g * 4];
      w.x = f2b(v.x); w.y = f2b(v.y); w.z = f2b(v.z); w.w = f2b(v.w);
    } else {
      const int kk = (g - 1024) * 4;   // 0..60
      float v0 = (kk + 0 < RANKD) ? 2.f * xA[(size_t)m * RANKD + kk + 0] : 0.f;
      float v1 = (kk + 1 < RANKD) ? 2.f * xA[(size_t)m * RANKD + kk + 1] : 0.f;
      float v2 = (kk + 2 < RANKD) ? 2.f * xA[(size_t)m * RANKD + kk + 2] : 0.f;
      float v3 = (kk + 3 < RANKD) ? 2.f * xA[(size_t)m * RANKD + kk + 3] : 0.f;
      w.x = f2b(v0); w.y = f2b(v1); w.z = f2b(v2); w.w = f2b(v3);
    }
    *(ushort4*)&Xe[(size_t)m * KE + g * 4] = w;
  }
}

// ------ kernel 3: We[o][0:4096]=bf16(dequant W), [4096:4112]=bf16(B[r][o]) ------
__global__ __launch_bounds__(256) void k_fill_we(const int* __restrict__ q,
                                                 const float* __restrict__ absmax,
                                                 const float* __restrict__ cb,
                                                 const float* __restrict__ B,
                                                 unsigned short* __restrict__ We) {
  __shared__ float cbs[16];
  if (threadIdx.x < 16) cbs[threadIdx.x] = cb[threadIdx.x];
  __syncthreads();
  const int total = OUTF * (KE / 4);
  for (int tid = blockIdx.x * 256 + threadIdx.x; tid < total;
       tid += 2048 * 256) {
    const int o = tid / 1040;
    const int g = tid - o * 1040;
    ushort4 w;
    if (g < 1024) {
      const int4 qc = *(const int4*)&q[(size_t)o * INF + g * 4];
      const float am = absmax[(size_t)o * 64 + (g >> 4)];
      w.x = f2b(cbs[qc.x] * am);
      w.y = f2b(cbs[qc.y] * am);
      w.z = f2b(cbs[qc.z] * am);
      w.w = f2b(cbs[qc.w] * am);
    } else {
      const int kk = (g - 1024) * 4;
      float v0 = (kk + 0 < RANKD) ? B[(size_t)(kk + 0) * OUTF + o] : 0.f;
      float v1 = (kk + 1 < RANKD) ? B[(size_t)(kk + 1) * OUTF + o] : 0.f;
      float v2 = (kk + 2 < RANKD) ? B[(size_t)(kk + 2) * OUTF + o] : 0.f;
      float v3 = (kk + 3 < RANKD) ? B[(size_t)(kk + 3) * OUTF + o] : 0.f;
      w.x = f2b(v0); w.y = f2b(v1); w.z = f2b(v2); w.w = f2b(v3);
    }
    *(ushort4*)&We[(size_t)o * KE + g * 4] = w;
  }
}

// ---------------- kernel 4: out = Xe @ We^T + bias ----------------
// 256x256 tile, BK=32, 8 waves (2Mx4N), 4-deep LDS ring (128 KB), counted vmcnt(4),
// one s_barrier per K-tile, XOR-swizzled LDS (both-sides), setprio around MFMA.
__global__ __launch_bounds__(512, 2) void k_gemm(const unsigned short* __restrict__ Xe,
                                                 const unsigned short* __restrict__ We,
                                                 const float* __restrict__ bias,
                                                 float* __restrict__ out) {
  extern __shared__ unsigned short LDS[];   // 4 bufs x (A 8192 + B 8192) ushorts = 128 KB

  const int tid  = threadIdx.x;
  const int lane = tid & 63;
  const int wave = tid >> 6;        // 0..7
  const int waveM = wave >> 2;      // 0..1 -> rows [waveM*128, +128)
  const int waveN = wave & 3;       // 0..3 -> cols [waveN*64, +64)

  // XCD-chunked bijective swizzle: 256 wgs, 32 per XCD = 2 tile-rows x 16 cols
  const int wg  = blockIdx.x;
  const int swz = (wg & 7) * 32 + (wg >> 3);
  const int trB = (swz >> 4) * 256;
  const int tcB = (swz & 15) * 256;

  // ---- staging constants (linear LDS dest, pre-swizzled global source) ----
  // dest byte d in tile: row = d>>6 (64B rows), logical in-row byte = (d&63) ^ ((row>>1&3)<<4)
  const int srow = lane >> 2;                                  // row within 16-row chunk
  const int wpr  = ((lane & 3) * 8) ^ (((lane >> 3) & 3) << 3); // ushort offset in row
  const unsigned short* gA0 = Xe + (size_t)(trB +       wave * 16 + srow) * KE + wpr;
  const unsigned short* gA1 = Xe + (size_t)(trB + 128 + wave * 16 + srow) * KE + wpr;
  const unsigned short* gB0 = We + (size_t)(tcB +       wave * 16 + srow) * KE + wpr;
  const unsigned short* gB1 = We + (size_t)(tcB + 128 + wave * 16 + srow) * KE + wpr;
  const int dA0 = wave * 512;            // ushort idx within buf (wave-uniform)
  const int dA1 = 4096 + wave * 512;
  const int dB0 = 8192 + wave * 512;
  const int dB1 = 12288 + wave * 512;

  // ---- fragment-read constants (swizzled byte offsets) ----
  const int fr = lane & 15;
  const int cb = (lane >> 4) * 16;                 // k-group byte offset
  const int sw = ((fr >> 1) & 3) << 4;
  const int aoff = (waveM * 128 + fr) * 64 + (cb ^ sw);           // byte in A region
  const int boff = 16384 + (waveN * 64 + fr) * 64 + (cb ^ sw);    // byte in B region

  f32x4 acc[8][4];
#pragma unroll
  for (int i = 0; i < 8; ++i)
#pragma unroll
    for (int j = 0; j < 4; ++j) acc[i][j] = f32x4{0.f, 0.f, 0.f, 0.f};

  // prologue: stage tiles 0 and 1
#pragma unroll
  for (int t = 0; t < 2; ++t) {
    const int sb = t * 16384;
    const int k0 = t * 32;
    gload_lds16(gA0 + k0, LDS + sb + dA0);
    gload_lds16(gA1 + k0, LDS + sb + dA1);
    gload_lds16(gB0 + k0, LDS + sb + dB0);
    gload_lds16(gB1 + k0, LDS + sb + dB1);
  }
  asm volatile("s_waitcnt vmcnt(4)" ::: "memory");   // tile 0 landed
  __builtin_amdgcn_s_barrier();

  for (int T = 0; T < NT; ++T) {
    const char* base = (const char*)LDS + (T & 3) * 32768;

    bf16x8 a[8], b[4];
#pragma unroll
    for (int i = 0; i < 8; ++i)
      a[i] = *(const bf16x8*)(base + aoff + i * 1024);
#pragma unroll
    for (int j = 0; j < 4; ++j)
      b[j] = *(const bf16x8*)(base + boff + j * 1024);

    if (T + 2 < NT) {                     // stage tile T+2 (buf last read at tile T-2)
      const int sb = ((T + 2) & 3) * 16384;
      const int k0 = (T + 2) * 32;
      gload_lds16(gA0 + k0, LDS + sb + dA0);
      gload_lds16(gA1 + k0, LDS + sb + dA1);
      gload_lds16(gB0 + k0, LDS + sb + dB0);
      gload_lds16(gB1 + k0, LDS + sb + dB1);
    }

    __builtin_amdgcn_s_setprio(1);
#pragma unroll
    for (int i = 0; i < 8; ++i)
#pragma unroll
      for (int j = 0; j < 4; ++j)
        acc[i][j] = __builtin_amdgcn_mfma_f32_16x16x32_bf16(a[i], b[j], acc[i][j], 0, 0, 0);
    __builtin_amdgcn_s_setprio(0);

    // retire tile T+1's 4 loads (issued at T-1); keep T+2's batch in flight
    asm volatile("s_waitcnt vmcnt(4)" ::: "memory");
    __builtin_amdgcn_s_barrier();
  }

  // epilogue: C/D layout col = lane&15, row = (lane>>4)*4 + reg
  const int rq = (lane >> 4) * 4;
#pragma unroll
  for (int j = 0; j < 4; ++j) {
    const int n = tcB + waveN * 64 + j * 16 + fr;
    const float bsv = bias[n];
#pragma unroll
    for (int i = 0; i < 8; ++i) {
      const int m = trB + waveM * 128 + i * 16 + rq;
#pragma unroll
      for (int e = 0; e < 4; ++e)
        out[(size_t)(m + e) * OUTF + n] = acc[i][j][e] + bsv;
    }
  }
}

extern "C" void kernel_launch(void* const* d_in, const int* in_sizes, int n_in,
                              void* d_out, int out_size, void* d_ws, size_t ws_size,
                              hipStream_t stream) {
  const float* x      = (const float*)d_in[0];
  const int*   q      = (const int*)d_in[1];
  const float* absmax = (const float*)d_in[2];
  const float* cb     = (const float*)d_in[3];
  const float* bias   = (const float*)d_in[4];
  const float* A      = (const float*)d_in[5];
  const float* B      = (const float*)d_in[6];
  float* out = (float*)d_out;

  unsigned short* Xe = (unsigned short*)d_ws;              // 4096*4160*2 B
  unsigned short* We = Xe + (size_t)TOK * KE;              // 4096*4160*2 B
  float* xA = (float*)(We + (size_t)OUTF * KE);            // 4096*16*4 B

  hipFuncSetAttribute((const void*)k_gemm,
                      hipFuncAttributeMaxDynamicSharedMemorySize, 131072);

  k_xa<<<TOK / 16, 256, 0, stream>>>(x, A, xA);
  k_fill_xe<<<2048, 256, 0, stream>>>(x, xA, Xe);
  k_fill_we<<<2048, 256, 0, stream>>>(q, absmax, cb, B, We);
  k_gemm<<<256, 512, 131072, stream>>>(Xe, We, bias, out);
}